// Round 10
// baseline (354.483 us; speedup 1.0000x reference)
//
#include <hip/hip_runtime.h>
#include <hip/hip_fp16.h>

#define NNODES 50000
#define NEDGES 800000
#define NEG_SLOPE 0.2f
#define NTOT (NEDGES + NNODES)
#define NB_NODE ((NNODES + 255) / 256)   // 196 buckets of 256 nodes
#define SLOTS 8
#define CAP 1024                          // per-(bucket,slot): mean 512, sigma ~23 -> +22 sigma

typedef _Float16 half8 __attribute__((ext_vector_type(8)));
typedef _Float16 half4 __attribute__((ext_vector_type(4)));
typedef float f32x4 __attribute__((ext_vector_type(4)));

// ---------------- setup: bucket cursors=0, W2T, x16, folded att dots ----------------
__global__ void setup_kernel(const float* __restrict__ x, const float* __restrict__ W1,
                             const float* __restrict__ att_src, const float* __restrict__ att_dst,
                             const float* __restrict__ W2,
                             int* __restrict__ bucket_cnt, float* __restrict__ x16,
                             float* __restrict__ asrc4, float* __restrict__ adst4,
                             _Float16* __restrict__ W2T) {
    int b = blockIdx.x, t = threadIdx.x;
    __shared__ float swa[16][4], swd[16][4];
    if (t < 128) {
        int k = (t & 63) >> 2, h = t & 3;
        float s = 0.f;
        if (k < 15) {
            const float* att = (t < 64) ? att_src : att_dst;
#pragma unroll 16
            for (int d = 0; d < 64; ++d)
                s += W1[k * 256 + h * 64 + d] * att[h * 64 + d];
        }
        if (t < 64) swa[k][h] = s; else swd[k][h] = s;
    }
    int tid = b * 256 + t;
    if (tid < NB_NODE * SLOTS) bucket_cnt[tid] = 0;
    // W2 [256][64] f32 -> W2T [64][256] f16
    if (tid < 64 * 256) {
        int n = tid >> 8, k = tid & 255;
        W2T[n * 256 + k] = (_Float16)W2[k * 64 + n];
    }
    __syncthreads();
    int nid = tid;
    if (nid < NNODES) {
        float xv[16];
#pragma unroll
        for (int k = 0; k < 15; ++k) xv[k] = x[nid * 15 + k];
        xv[15] = 0.f;
#pragma unroll
        for (int k = 0; k < 16; k += 4)
            *(float4*)(x16 + (size_t)nid * 16 + k) = make_float4(xv[k], xv[k+1], xv[k+2], xv[k+3]);
        float ps[4] = {0.f, 0.f, 0.f, 0.f}, pd[4] = {0.f, 0.f, 0.f, 0.f};
#pragma unroll
        for (int k = 0; k < 15; ++k)
#pragma unroll
            for (int h = 0; h < 4; ++h) {
                ps[h] += xv[k] * swa[k][h];
                pd[h] += xv[k] * swd[k][h];
            }
        *(float4*)(asrc4 + nid * 4) = make_float4(ps[0], ps[1], ps[2], ps[3]);
        *(float4*)(adst4 + nid * 4) = make_float4(pd[0], pd[1], pd[2], pd[3]);
    }
}

// ---------------- pass 1: bucketed append, REAL edges only ----------------
// entry = (dst&255)<<16 | src (src < 2^16). Slot by blockIdx&7: per-cell load
// is 512 +- 23 (self-loops are inserted directly in local_sort, not here).
__global__ void bucket_scatter(const int* __restrict__ srcs, const int* __restrict__ dsts,
                               int* __restrict__ bucket_cnt, int* __restrict__ bucketbuf) {
    int e = blockIdx.x * 256 + threadIdx.x;
    int g = blockIdx.x & (SLOTS - 1);
    if (e < NEDGES) {
        int s = srcs[e], d = dsts[e];
        int cell = (d >> 8) * SLOTS + g;
        int pos = atomicAdd(&bucket_cnt[cell], 1);
        if (pos < CAP) bucketbuf[cell * CAP + pos] = ((d & 255) << 16) | s;
    }
}

// ---------------- scanA: per-bucket LDS histogram (+1 self-loop) + scan ----------------
__global__ void scanA(const int* __restrict__ bucket_cnt, const int* __restrict__ bucketbuf,
                      int* __restrict__ rowstart, int* __restrict__ partials) {
    int b = blockIdx.x, t = threadIdx.x, lane = t & 63, wid = t >> 6;
    __shared__ int hist[256];
    __shared__ int ws[4];
    int i = b * 256 + t;
    hist[t] = (i < NNODES) ? 1 : 0;          // self-loop counted here
    __syncthreads();
#pragma unroll
    for (int g = 0; g < SLOTS; ++g) {
        int cell = b * SLOTS + g;
        int n = bucket_cnt[cell]; if (n > CAP) n = CAP;
        const int* buf = bucketbuf + (size_t)cell * CAP;
        for (int j = t; j < n; j += 256)
            atomicAdd(&hist[buf[j] >> 16], 1);
    }
    __syncthreads();
    int v = (i < NNODES) ? hist[t] : 0;
    int incl = v;
#pragma unroll
    for (int off = 1; off < 64; off <<= 1) {
        int u = __shfl_up(incl, off, 64);
        if (lane >= off) incl += u;
    }
    if (lane == 63) ws[wid] = incl;
    __syncthreads();
    int w0 = ws[0], w1 = ws[1], w2 = ws[2], w3 = ws[3];
    int woff = (wid > 0 ? w0 : 0) + (wid > 1 ? w1 : 0) + (wid > 2 ? w2 : 0);
    if (i < NNODES) rowstart[i] = woff + (incl - v);
    if (t == 0) partials[b] = w0 + w1 + w2 + w3;
}

__global__ void scanB(const int* __restrict__ partials, int* __restrict__ blockoff,
                      int* __restrict__ rowstart, int nb) {
    int t = threadIdx.x, lane = t & 63, wid = t >> 6;
    int v = (t < nb) ? partials[t] : 0;
    int incl = v;
#pragma unroll
    for (int off = 1; off < 64; off <<= 1) {
        int u = __shfl_up(incl, off, 64);
        if (lane >= off) incl += u;
    }
    __shared__ int ws[4];
    if (lane == 63) ws[wid] = incl;
    __syncthreads();
    int w0 = ws[0], w1 = ws[1], w2 = ws[2], w3 = ws[3];
    int woff = (wid > 0 ? w0 : 0) + (wid > 1 ? w1 : 0) + (wid > 2 ? w2 : 0);
    if (t < nb) blockoff[t] = woff + (incl - v);
    // total from actual counts (consistent even under hypothetical drops)
    if (t == 0) rowstart[NNODES] = w0 + w1 + w2 + w3;
}

__global__ void scanC(int* __restrict__ rowstart, const int* __restrict__ blockoff) {
    int b = blockIdx.x, t = threadIdx.x;
    int i = b * 256 + t;
    if (i < NNODES) rowstart[i] += blockoff[b];
}

// ---------------- pass 2b: LDS counting sort + direct self-loop insert ----------------
__global__ void local_sort(const int* __restrict__ bucket_cnt, const int* __restrict__ bucketbuf,
                           const int* __restrict__ rowstart, int* __restrict__ srclist) {
    int b = blockIdx.x, t = threadIdx.x;
    __shared__ int cur[256];
    __shared__ int local[8192];   // max bucket load ~4.6k; huge margin
    int idx = b * 256 + t; if (idx > NNODES) idx = NNODES;
    int base = rowstart[b * 256];
    cur[t] = rowstart[idx] - base;
    __syncthreads();
    int nid = b * 256 + t;
    if (nid < NNODES) {                        // self-loop inserted directly
        int pos = atomicAdd(&cur[t], 1);
        local[pos] = nid;                      // nid < 2^16
    }
#pragma unroll
    for (int g = 0; g < SLOTS; ++g) {
        int cell = b * SLOTS + g;
        int n = bucket_cnt[cell]; if (n > CAP) n = CAP;
        const int* buf = bucketbuf + (size_t)cell * CAP;
        for (int i = t; i < n; i += 256) {
            int entry = buf[i];
            int pos = atomicAdd(&cur[entry >> 16], 1);
            local[pos] = entry & 0xFFFF;
        }
    }
    __syncthreads();
    int endidx = (b + 1) * 256; if (endidx > NNODES) endidx = NNODES;
    int total = rowstart[endidx] - base;
    for (int i = t; i < total; i += 256) srclist[base + i] = local[i];
}

// ---------------- layer 1: fused aggregate + projection (linearity) ----------------
// sum_e w_e*h1[src_e] = (sum_e w_e*x[src_e]) @ W1. One wave per node; x16/asrc4
// gathers are L2-resident. 4 edges in flight. No cross-lane reduction.
__global__ void layer1_aggr(const float* __restrict__ x16, const int* __restrict__ rowstart,
                            const int* __restrict__ srclist,
                            const float* __restrict__ asrc4, const float* __restrict__ adst4,
                            const float* __restrict__ W1, const float* __restrict__ b1,
                            __half* __restrict__ out1) {
    int wid = threadIdx.x >> 6, lane = threadIdx.x & 63;
    int nid = blockIdx.x * 4 + wid;
    int h = lane >> 4, k = lane & 15;
    int beg = __builtin_amdgcn_readfirstlane(rowstart[nid]);
    int end = __builtin_amdgcn_readfirstlane(rowstart[nid + 1]);
    float ad = adst4[nid * 4 + h];
    float acc = 0.f, zs = 0.f;
    int nfull = beg + ((end - beg) & ~3);
    for (int i0 = beg; i0 < nfull; i0 += 4) {          // 4 independent L2-hit gathers
        int s0 = srclist[i0];                          // uniform -> s_load
        int s1 = srclist[i0 + 1];
        int s2 = srclist[i0 + 2];
        int s3 = srclist[i0 + 3];
        float xv0 = x16[s0 * 16 + k];
        float xv1 = x16[s1 * 16 + k];
        float xv2 = x16[s2 * 16 + k];
        float xv3 = x16[s3 * 16 + k];
        float e0 = asrc4[s0 * 4 + h] + ad;
        float e1 = asrc4[s1 * 4 + h] + ad;
        float e2 = asrc4[s2 * 4 + h] + ad;
        float e3 = asrc4[s3 * 4 + h] + ad;
        e0 = fmaxf(e0, NEG_SLOPE * e0); e1 = fmaxf(e1, NEG_SLOPE * e1);
        e2 = fmaxf(e2, NEG_SLOPE * e2); e3 = fmaxf(e3, NEG_SLOPE * e3);
        float w0 = __expf(e0), w1 = __expf(e1), w2 = __expf(e2), w3 = __expf(e3);
        zs += w0 + w1 + w2 + w3;
        acc = fmaf(w0, xv0, acc);
        acc = fmaf(w1, xv1, acc);
        acc = fmaf(w2, xv2, acc);
        acc = fmaf(w3, xv3, acc);
    }
    for (int i = nfull; i < end; ++i) {
        int s = srclist[i];
        float xv = x16[s * 16 + k];
        float e = asrc4[s * 4 + h] + ad;
        e = fmaxf(e, NEG_SLOPE * e);
        float w = __expf(e);
        zs += w;
        acc = fmaf(w, xv, acc);
    }
    __shared__ float sacc[4][64];
    sacc[wid][lane] = acc * (1.f / zs);                // wave-coherent: no barrier needed
    int c = lane, h2 = c >> 4;                         // lane -> out dims c*4..c*4+3
    float o0 = 0.f, o1 = 0.f, o2 = 0.f, o3 = 0.f;
#pragma unroll
    for (int kk = 0; kk < 15; ++kk) {
        float a = sacc[wid][h2 * 16 + kk];             // broadcast within 16-lane group
        float4 wv = *(const float4*)(W1 + kk * 256 + c * 4);   // L1-resident (15 KB)
        o0 = fmaf(a, wv.x, o0); o1 = fmaf(a, wv.y, o1);
        o2 = fmaf(a, wv.z, o2); o3 = fmaf(a, wv.w, o3);
    }
    float4 bo = *(const float4*)(b1 + c * 4);
    o0 += bo.x; o1 += bo.y; o2 += bo.z; o3 += bo.w;
    o0 = o0 > 0.f ? o0 : __expf(o0) - 1.f;             // ELU
    o1 = o1 > 0.f ? o1 : __expf(o1) - 1.f;
    o2 = o2 > 0.f ? o2 : __expf(o2) - 1.f;
    o3 = o3 > 0.f ? o3 : __expf(o3) - 1.f;
    half4 st;
    st[0] = (_Float16)o0; st[1] = (_Float16)o1; st[2] = (_Float16)o2; st[3] = (_Float16)o3;
    *(half4*)((_Float16*)out1 + (size_t)nid * 256 + c * 4) = st;
}

// ---------------- layer 2 ----------------

// MFMA GEMM: h2[50000x64] = out1[50000x256] @ W2, fused attention dots.
__global__ __launch_bounds__(256) void layer2_gemm(const __half* __restrict__ out1,
                                                   const _Float16* __restrict__ W2T,
                                                   __half* __restrict__ h2,
                                                   const float* __restrict__ att_src2,
                                                   const float* __restrict__ att_dst2,
                                                   float* __restrict__ as2,
                                                   float* __restrict__ ad2) {
    int w = threadIdx.x >> 6, lane = threadIdx.x & 63;
    int m16 = lane & 15, quad = lane >> 4;
    int r0 = blockIdx.x * 64 + w * 16;
    const _Float16* A = (const _Float16*)out1;
    f32x4 acc[4] = {{0.f,0.f,0.f,0.f},{0.f,0.f,0.f,0.f},{0.f,0.f,0.f,0.f},{0.f,0.f,0.f,0.f}};
    int row = r0 + m16; if (row >= NNODES) row = NNODES - 1;   // clamp tail reads
#pragma unroll
    for (int k0 = 0; k0 < 256; k0 += 32) {
        half8 a = *(const half8*)(A + (size_t)row * 256 + k0 + quad * 8);
#pragma unroll
        for (int nt = 0; nt < 4; ++nt) {
            half8 b = *(const half8*)(W2T + (size_t)(nt * 16 + m16) * 256 + k0 + quad * 8);
            acc[nt] = __builtin_amdgcn_mfma_f32_16x16x32_f16(a, b, acc[nt], 0, 0, 0);
        }
    }
    __shared__ _Float16 tile[64][72];
#pragma unroll
    for (int nt = 0; nt < 4; ++nt)
#pragma unroll
        for (int r = 0; r < 4; ++r)
            tile[w * 16 + quad * 4 + r][nt * 16 + m16] = (_Float16)acc[nt][r];
    __syncthreads();
    int t = threadIdx.x;
    int trow = t >> 2, seg = t & 3;
    int rg = blockIdx.x * 64 + trow;
    if (rg < NNODES) {
        float4 v0 = *(float4*)&tile[trow][seg * 16];
        float4 v1 = *(float4*)&tile[trow][seg * 16 + 8];
        _Float16* dst = (_Float16*)h2 + (size_t)rg * 64 + seg * 16;
        *(float4*)dst = v0;
        *(float4*)(dst + 8) = v1;
        const _Float16* hv = &tile[trow][seg * 16];
        float ps = 0.f, pd = 0.f;
#pragma unroll
        for (int j = 0; j < 16; ++j) {
            float v = (float)hv[j];
            ps += v * att_src2[seg * 16 + j];
            pd += v * att_dst2[seg * 16 + j];
        }
        ps += __shfl_xor(ps, 1, 64); ps += __shfl_xor(ps, 2, 64);
        pd += __shfl_xor(pd, 1, 64); pd += __shfl_xor(pd, 2, 64);
        if (seg == 0) { as2[rg] = ps; ad2[rg] = pd; }
    }
}

// one wave per node; 4 groups of 16 lanes x 4 edges per iteration = 16 gathers in flight.
__global__ void layer2_aggr(const __half* __restrict__ h2, const int* __restrict__ rowstart,
                            const int* __restrict__ srclist,
                            const float* __restrict__ as2, const float* __restrict__ ad2,
                            const float* __restrict__ b2, float* __restrict__ out2) {
    int wid = threadIdx.x >> 6, lane = threadIdx.x & 63;
    int nid = blockIdx.x * 4 + wid;
    int q = lane >> 4, c = lane & 15;
    int beg = __builtin_amdgcn_readfirstlane(rowstart[nid]);
    int end = __builtin_amdgcn_readfirstlane(rowstart[nid + 1]);
    float ad = ad2[nid];
    const __half* hb = h2 + c * 4;
    __half2 z16 = __float2half2_rn(0.f);
    __half2 acc0 = z16, acc1 = z16;
    float zs = 0.f;
    for (int i0 = beg; i0 < end; i0 += 16) {
#pragma unroll
        for (int u = 0; u < 4; ++u) {
            int i = i0 + q + 4 * u;
            bool valid = i < end;
            int s = valid ? srclist[i] : 0;
            float2 gv = *(const float2*)(hb + (size_t)s * 64);   // 8 B = 4 dims
            float e = as2[s] + ad;
            e = fmaxf(e, NEG_SLOPE * e);
            float w = valid ? __expf(e) : 0.f;
            zs += w;
            __half2 wh = __float2half2_rn(w);
            acc0 = __hfma2(wh, *(__half2*)&gv.x, acc0);
            acc1 = __hfma2(wh, *(__half2*)&gv.y, acc1);
        }
    }
    float2 f0 = __half22float2(acc0), f1 = __half22float2(acc1);
    float ax = f0.x, ay = f0.y, az = f1.x, aw = f1.y;
#pragma unroll
    for (int off = 16; off < 64; off <<= 1) {
        ax += __shfl_xor(ax, off, 64);
        ay += __shfl_xor(ay, off, 64);
        az += __shfl_xor(az, off, 64);
        aw += __shfl_xor(aw, off, 64);
        zs += __shfl_xor(zs, off, 64);
    }
    if (lane < 16) {
        float rz = 1.f / zs;
        float4 bo = ((const float4*)b2)[c];
        float4 st = make_float4(ax * rz + bo.x, ay * rz + bo.y,
                                az * rz + bo.z, aw * rz + bo.w);
        *(float4*)(out2 + (size_t)nid * 64 + c * 4) = st;
    }
}

// ---------------- final mean over nodes ----------------

__global__ void reduce_kernel(const float* __restrict__ out2, float* __restrict__ dout) {
    int t = threadIdx.x;
    int col = t & 63, sub = t >> 6;
    float acc = 0.f;
    for (int r = blockIdx.x * 4 + sub; r < NNODES; r += 256 * 4)
        acc += out2[r * 64 + col];
    __shared__ float sh[256];
    sh[t] = acc;
    __syncthreads();
    if (t < 64) {
        float v = sh[t] + sh[t + 64] + sh[t + 128] + sh[t + 192];
        atomicAdd(&dout[t], v * (1.0f / NNODES));
    }
}

// ---------------- launch ----------------

extern "C" void kernel_launch(void* const* d_in, const int* in_sizes, int n_in,
                              void* d_out, int out_size, void* d_ws, size_t ws_size,
                              hipStream_t stream) {
    const float* x        = (const float*)d_in[0];
    const int*   ei       = (const int*)d_in[1];   // [2, E] -> src row then dst row
    const float* W1       = (const float*)d_in[2];
    const float* att_src1 = (const float*)d_in[3];
    const float* att_dst1 = (const float*)d_in[4];
    const float* b1       = (const float*)d_in[5];
    const float* W2       = (const float*)d_in[6];
    const float* att_src2 = (const float*)d_in[7];
    const float* att_dst2 = (const float*)d_in[8];
    const float* b2       = (const float*)d_in[9];
    float* out = (float*)d_out;

    char* ws = (char*)d_ws;
    size_t off = 0;
    auto take = [&](size_t bytes) -> char* {
        char* p = ws + off;
        off = (off + bytes + 255) & ~(size_t)255;
        return p;
    };
    int*      bucket_cnt = (int*)take((size_t)NB_NODE * SLOTS * sizeof(int));
    int*      bucketbuf  = (int*)take((size_t)NB_NODE * SLOTS * CAP * sizeof(int));
    int*      rowstart   = (int*)take((NNODES + 1) * sizeof(int));
    int*      partials   = (int*)take(256 * sizeof(int));
    int*      blockoff   = (int*)take(256 * sizeof(int));
    int*      srclist    = (int*)take(((size_t)NTOT + 16) * sizeof(int));
    float*    x16        = (float*)take((size_t)NNODES * 16 * sizeof(float));
    float*    asrc4      = (float*)take((size_t)NNODES * 4 * sizeof(float));
    float*    adst4      = (float*)take((size_t)NNODES * 4 * sizeof(float));
    __half*   out1       = (__half*)take((size_t)NNODES * 256 * sizeof(__half));
    _Float16* W2T        = (_Float16*)take(64 * 256 * sizeof(_Float16));
    __half*   h2         = (__half*)take((size_t)NNODES * 64 * sizeof(__half));
    float*    as2        = (float*)take((size_t)NNODES * sizeof(float));
    float*    ad2        = (float*)take((size_t)NNODES * sizeof(float));
    float*    out2       = (float*)take((size_t)NNODES * 64 * sizeof(float));

    const int* srcs = ei;
    const int* dsts = ei + NEDGES;

    hipMemsetAsync(d_out, 0, 64 * sizeof(float), stream);

    setup_kernel<<<NB_NODE, 256, 0, stream>>>(x, W1, att_src1, att_dst1, W2,
                                              bucket_cnt, x16, asrc4, adst4, W2T);
    bucket_scatter<<<(NEDGES + 255) / 256, 256, 0, stream>>>(srcs, dsts, bucket_cnt, bucketbuf);
    scanA<<<NB_NODE, 256, 0, stream>>>(bucket_cnt, bucketbuf, rowstart, partials);
    scanB<<<1, 256, 0, stream>>>(partials, blockoff, rowstart, NB_NODE);
    scanC<<<NB_NODE, 256, 0, stream>>>(rowstart, blockoff);
    local_sort<<<NB_NODE, 256, 0, stream>>>(bucket_cnt, bucketbuf, rowstart, srclist);

    layer1_aggr<<<NNODES / 4, 256, 0, stream>>>(x16, rowstart, srclist, asrc4, adst4,
                                                W1, b1, out1);

    layer2_gemm<<<(NNODES + 63) / 64, 256, 0, stream>>>(out1, W2T, h2, att_src2, att_dst2,
                                                        as2, ad2);
    layer2_aggr<<<NNODES / 4, 256, 0, stream>>>(h2, rowstart, srclist, as2, ad2, b2, out2);

    reduce_kernel<<<256, 256, 0, stream>>>(out2, out);
}

// Round 11
// 223.145 us; speedup vs baseline: 1.5886x; 1.5886x over previous
//
#include <hip/hip_runtime.h>
#include <hip/hip_fp16.h>

#define NNODES 50000
#define NEDGES 800000
#define NEG_SLOPE 0.2f
#define NTOT (NEDGES + NNODES)
#define NB_NODE ((NNODES + 255) / 256)   // 196 buckets of 256 nodes
#define CHUNK 4096
#define NCHUNK ((NEDGES + CHUNK - 1) / CHUNK)   // 196 chunks
#define CAPB 4800                         // per-bucket capacity: mean 4082, sigma ~64 -> +11 sigma
#define CNTSTRIDE 16                      // 64 B padding: one counter per cache line

typedef _Float16 half8 __attribute__((ext_vector_type(8)));
typedef _Float16 half4 __attribute__((ext_vector_type(4)));
typedef float f32x4 __attribute__((ext_vector_type(4)));

// ---------------- setup: padded bucket counters=0, W2T, x16, folded att dots ----------------
__global__ void setup_kernel(const float* __restrict__ x, const float* __restrict__ W1,
                             const float* __restrict__ att_src, const float* __restrict__ att_dst,
                             const float* __restrict__ W2,
                             int* __restrict__ bucket_cnt, float* __restrict__ x16,
                             float* __restrict__ asrc4, float* __restrict__ adst4,
                             _Float16* __restrict__ W2T) {
    int b = blockIdx.x, t = threadIdx.x;
    __shared__ float swa[16][4], swd[16][4];
    if (t < 128) {
        int k = (t & 63) >> 2, h = t & 3;
        float s = 0.f;
        if (k < 15) {
            const float* att = (t < 64) ? att_src : att_dst;
#pragma unroll 16
            for (int d = 0; d < 64; ++d)
                s += W1[k * 256 + h * 64 + d] * att[h * 64 + d];
        }
        if (t < 64) swa[k][h] = s; else swd[k][h] = s;
    }
    int tid = b * 256 + t;
    if (tid < NB_NODE * CNTSTRIDE) bucket_cnt[tid] = 0;
    // W2 [256][64] f32 -> W2T [64][256] f16
    if (tid < 64 * 256) {
        int n = tid >> 8, k = tid & 255;
        W2T[n * 256 + k] = (_Float16)W2[k * 64 + n];
    }
    __syncthreads();
    int nid = tid;
    if (nid < NNODES) {
        float xv[16];
#pragma unroll
        for (int k = 0; k < 15; ++k) xv[k] = x[nid * 15 + k];
        xv[15] = 0.f;
#pragma unroll
        for (int k = 0; k < 16; k += 4)
            *(float4*)(x16 + (size_t)nid * 16 + k) = make_float4(xv[k], xv[k+1], xv[k+2], xv[k+3]);
        float ps[4] = {0.f, 0.f, 0.f, 0.f}, pd[4] = {0.f, 0.f, 0.f, 0.f};
#pragma unroll
        for (int k = 0; k < 15; ++k)
#pragma unroll
            for (int h = 0; h < 4; ++h) {
                ps[h] += xv[k] * swa[k][h];
                pd[h] += xv[k] * swd[k][h];
            }
        *(float4*)(asrc4 + nid * 4) = make_float4(ps[0], ps[1], ps[2], ps[3]);
        *(float4*)(adst4 + nid * 4) = make_float4(pd[0], pd[1], pd[2], pd[3]);
    }
}

// ---------------- bucketed scatter: chunk-local count -> reserve -> scatter ----------------
// 196 blocks x 4096-edge chunks. LDS histogram (196 counters) -> ONE padded global
// atomic per (block,bucket) range-reservation -> LDS-cursor scatter. Entry =
// (dst&255)<<16 | src; dst < 2^16 so the full dst is stashed in LDS as ushort.
__global__ void bucket_scatter(const int* __restrict__ srcs, const int* __restrict__ dsts,
                               int* __restrict__ bucket_cnt, int* __restrict__ bucketbuf) {
    int b = blockIdx.x, t = threadIdx.x;
    __shared__ unsigned short meta[CHUNK];
    __shared__ int lcnt[NB_NODE], lbase[NB_NODE];
    for (int i = t; i < NB_NODE; i += 256) lcnt[i] = 0;
    __syncthreads();
    int e0 = b * CHUNK;
    int e1 = e0 + CHUNK; if (e1 > NEDGES) e1 = NEDGES;
    for (int e = e0 + t; e < e1; e += 256) {
        int d = dsts[e];
        meta[e - e0] = (unsigned short)d;
        atomicAdd(&lcnt[d >> 8], 1);
    }
    __syncthreads();
    for (int i = t; i < NB_NODE; i += 256) {
        int c = lcnt[i];
        lbase[i] = c ? atomicAdd(&bucket_cnt[i * CNTSTRIDE], c) : 0;
    }
    __syncthreads();
    for (int i = t; i < NB_NODE; i += 256) lcnt[i] = 0;   // reuse as cursor
    __syncthreads();
    for (int e = e0 + t; e < e1; e += 256) {
        int dv = meta[e - e0];
        int bk = dv >> 8;
        int pos = lbase[bk] + atomicAdd(&lcnt[bk], 1);
        if (pos < CAPB) bucketbuf[bk * CAPB + pos] = ((dv & 255) << 16) | srcs[e];
    }
}

// ---------------- scanA: per-bucket LDS histogram (+1 self-loop) + scan ----------------
__global__ void scanA(const int* __restrict__ bucket_cnt, const int* __restrict__ bucketbuf,
                      int* __restrict__ rowstart, int* __restrict__ partials) {
    int b = blockIdx.x, t = threadIdx.x, lane = t & 63, wid = t >> 6;
    __shared__ int hist[256];
    __shared__ int ws[4];
    int i = b * 256 + t;
    hist[t] = (i < NNODES) ? 1 : 0;          // self-loop counted here
    __syncthreads();
    int n = bucket_cnt[b * CNTSTRIDE]; if (n > CAPB) n = CAPB;
    const int* buf = bucketbuf + (size_t)b * CAPB;
    for (int j = t; j < n; j += 256)
        atomicAdd(&hist[buf[j] >> 16], 1);
    __syncthreads();
    int v = (i < NNODES) ? hist[t] : 0;
    int incl = v;
#pragma unroll
    for (int off = 1; off < 64; off <<= 1) {
        int u = __shfl_up(incl, off, 64);
        if (lane >= off) incl += u;
    }
    if (lane == 63) ws[wid] = incl;
    __syncthreads();
    int w0 = ws[0], w1 = ws[1], w2 = ws[2], w3 = ws[3];
    int woff = (wid > 0 ? w0 : 0) + (wid > 1 ? w1 : 0) + (wid > 2 ? w2 : 0);
    if (i < NNODES) rowstart[i] = woff + (incl - v);
    if (t == 0) partials[b] = w0 + w1 + w2 + w3;
}

__global__ void scanB(const int* __restrict__ partials, int* __restrict__ blockoff,
                      int* __restrict__ rowstart, int nb) {
    int t = threadIdx.x, lane = t & 63, wid = t >> 6;
    int v = (t < nb) ? partials[t] : 0;
    int incl = v;
#pragma unroll
    for (int off = 1; off < 64; off <<= 1) {
        int u = __shfl_up(incl, off, 64);
        if (lane >= off) incl += u;
    }
    __shared__ int ws[4];
    if (lane == 63) ws[wid] = incl;
    __syncthreads();
    int w0 = ws[0], w1 = ws[1], w2 = ws[2], w3 = ws[3];
    int woff = (wid > 0 ? w0 : 0) + (wid > 1 ? w1 : 0) + (wid > 2 ? w2 : 0);
    if (t < nb) blockoff[t] = woff + (incl - v);
    // total from actual counts (consistent even under hypothetical drops)
    if (t == 0) rowstart[NNODES] = w0 + w1 + w2 + w3;
}

__global__ void scanC(int* __restrict__ rowstart, const int* __restrict__ blockoff) {
    int b = blockIdx.x, t = threadIdx.x;
    int i = b * 256 + t;
    if (i < NNODES) rowstart[i] += blockoff[b];
}

// ---------------- LDS counting sort + direct self-loop insert ----------------
__global__ void local_sort(const int* __restrict__ bucket_cnt, const int* __restrict__ bucketbuf,
                           const int* __restrict__ rowstart, int* __restrict__ srclist) {
    int b = blockIdx.x, t = threadIdx.x;
    __shared__ int cur[256];
    __shared__ int local[8192];   // max bucket load ~4.7k incl self-loops
    int idx = b * 256 + t; if (idx > NNODES) idx = NNODES;
    int base = rowstart[b * 256];
    cur[t] = rowstart[idx] - base;
    __syncthreads();
    int nid = b * 256 + t;
    if (nid < NNODES) {                        // self-loop inserted directly
        int pos = atomicAdd(&cur[t], 1);
        local[pos] = nid;                      // nid < 2^16
    }
    int n = bucket_cnt[b * CNTSTRIDE]; if (n > CAPB) n = CAPB;
    const int* buf = bucketbuf + (size_t)b * CAPB;
    for (int i = t; i < n; i += 256) {
        int entry = buf[i];
        int pos = atomicAdd(&cur[entry >> 16], 1);
        local[pos] = entry & 0xFFFF;
    }
    __syncthreads();
    int endidx = (b + 1) * 256; if (endidx > NNODES) endidx = NNODES;
    int total = rowstart[endidx] - base;
    for (int i = t; i < total; i += 256) srclist[base + i] = local[i];
}

// ---------------- layer 1: fused aggregate + projection (linearity) ----------------
// sum_e w_e*h1[src_e] = (sum_e w_e*x[src_e]) @ W1. One wave per node; x16/asrc4
// gathers are L2-resident. 4 edges in flight. No cross-lane reduction.
__global__ void layer1_aggr(const float* __restrict__ x16, const int* __restrict__ rowstart,
                            const int* __restrict__ srclist,
                            const float* __restrict__ asrc4, const float* __restrict__ adst4,
                            const float* __restrict__ W1, const float* __restrict__ b1,
                            __half* __restrict__ out1) {
    int wid = threadIdx.x >> 6, lane = threadIdx.x & 63;
    int nid = blockIdx.x * 4 + wid;
    int h = lane >> 4, k = lane & 15;
    int beg = __builtin_amdgcn_readfirstlane(rowstart[nid]);
    int end = __builtin_amdgcn_readfirstlane(rowstart[nid + 1]);
    float ad = adst4[nid * 4 + h];
    float acc = 0.f, zs = 0.f;
    int nfull = beg + ((end - beg) & ~3);
    for (int i0 = beg; i0 < nfull; i0 += 4) {          // 4 independent L2-hit gathers
        int s0 = srclist[i0];                          // uniform -> s_load
        int s1 = srclist[i0 + 1];
        int s2 = srclist[i0 + 2];
        int s3 = srclist[i0 + 3];
        float xv0 = x16[s0 * 16 + k];
        float xv1 = x16[s1 * 16 + k];
        float xv2 = x16[s2 * 16 + k];
        float xv3 = x16[s3 * 16 + k];
        float e0 = asrc4[s0 * 4 + h] + ad;
        float e1 = asrc4[s1 * 4 + h] + ad;
        float e2 = asrc4[s2 * 4 + h] + ad;
        float e3 = asrc4[s3 * 4 + h] + ad;
        e0 = fmaxf(e0, NEG_SLOPE * e0); e1 = fmaxf(e1, NEG_SLOPE * e1);
        e2 = fmaxf(e2, NEG_SLOPE * e2); e3 = fmaxf(e3, NEG_SLOPE * e3);
        float w0 = __expf(e0), w1 = __expf(e1), w2 = __expf(e2), w3 = __expf(e3);
        zs += w0 + w1 + w2 + w3;
        acc = fmaf(w0, xv0, acc);
        acc = fmaf(w1, xv1, acc);
        acc = fmaf(w2, xv2, acc);
        acc = fmaf(w3, xv3, acc);
    }
    for (int i = nfull; i < end; ++i) {
        int s = srclist[i];
        float xv = x16[s * 16 + k];
        float e = asrc4[s * 4 + h] + ad;
        e = fmaxf(e, NEG_SLOPE * e);
        float w = __expf(e);
        zs += w;
        acc = fmaf(w, xv, acc);
    }
    __shared__ float sacc[4][64];
    sacc[wid][lane] = acc * (1.f / zs);                // wave-coherent: no barrier needed
    int c = lane, h2 = c >> 4;                         // lane -> out dims c*4..c*4+3
    float o0 = 0.f, o1 = 0.f, o2 = 0.f, o3 = 0.f;
#pragma unroll
    for (int kk = 0; kk < 15; ++kk) {
        float a = sacc[wid][h2 * 16 + kk];             // broadcast within 16-lane group
        float4 wv = *(const float4*)(W1 + kk * 256 + c * 4);   // L1-resident (15 KB)
        o0 = fmaf(a, wv.x, o0); o1 = fmaf(a, wv.y, o1);
        o2 = fmaf(a, wv.z, o2); o3 = fmaf(a, wv.w, o3);
    }
    float4 bo = *(const float4*)(b1 + c * 4);
    o0 += bo.x; o1 += bo.y; o2 += bo.z; o3 += bo.w;
    o0 = o0 > 0.f ? o0 : __expf(o0) - 1.f;             // ELU
    o1 = o1 > 0.f ? o1 : __expf(o1) - 1.f;
    o2 = o2 > 0.f ? o2 : __expf(o2) - 1.f;
    o3 = o3 > 0.f ? o3 : __expf(o3) - 1.f;
    half4 st;
    st[0] = (_Float16)o0; st[1] = (_Float16)o1; st[2] = (_Float16)o2; st[3] = (_Float16)o3;
    *(half4*)((_Float16*)out1 + (size_t)nid * 256 + c * 4) = st;
}

// ---------------- layer 2 ----------------

// MFMA GEMM: h2[50000x64] = out1[50000x256] @ W2, fused attention dots.
__global__ __launch_bounds__(256) void layer2_gemm(const __half* __restrict__ out1,
                                                   const _Float16* __restrict__ W2T,
                                                   __half* __restrict__ h2,
                                                   const float* __restrict__ att_src2,
                                                   const float* __restrict__ att_dst2,
                                                   float* __restrict__ as2,
                                                   float* __restrict__ ad2) {
    int w = threadIdx.x >> 6, lane = threadIdx.x & 63;
    int m16 = lane & 15, quad = lane >> 4;
    int r0 = blockIdx.x * 64 + w * 16;
    const _Float16* A = (const _Float16*)out1;
    f32x4 acc[4] = {{0.f,0.f,0.f,0.f},{0.f,0.f,0.f,0.f},{0.f,0.f,0.f,0.f},{0.f,0.f,0.f,0.f}};
    int row = r0 + m16; if (row >= NNODES) row = NNODES - 1;   // clamp tail reads
#pragma unroll
    for (int k0 = 0; k0 < 256; k0 += 32) {
        half8 a = *(const half8*)(A + (size_t)row * 256 + k0 + quad * 8);
#pragma unroll
        for (int nt = 0; nt < 4; ++nt) {
            half8 b = *(const half8*)(W2T + (size_t)(nt * 16 + m16) * 256 + k0 + quad * 8);
            acc[nt] = __builtin_amdgcn_mfma_f32_16x16x32_f16(a, b, acc[nt], 0, 0, 0);
        }
    }
    __shared__ _Float16 tile[64][72];
#pragma unroll
    for (int nt = 0; nt < 4; ++nt)
#pragma unroll
        for (int r = 0; r < 4; ++r)
            tile[w * 16 + quad * 4 + r][nt * 16 + m16] = (_Float16)acc[nt][r];
    __syncthreads();
    int t = threadIdx.x;
    int trow = t >> 2, seg = t & 3;
    int rg = blockIdx.x * 64 + trow;
    if (rg < NNODES) {
        float4 v0 = *(float4*)&tile[trow][seg * 16];
        float4 v1 = *(float4*)&tile[trow][seg * 16 + 8];
        _Float16* dst = (_Float16*)h2 + (size_t)rg * 64 + seg * 16;
        *(float4*)dst = v0;
        *(float4*)(dst + 8) = v1;
        const _Float16* hv = &tile[trow][seg * 16];
        float ps = 0.f, pd = 0.f;
#pragma unroll
        for (int j = 0; j < 16; ++j) {
            float v = (float)hv[j];
            ps += v * att_src2[seg * 16 + j];
            pd += v * att_dst2[seg * 16 + j];
        }
        ps += __shfl_xor(ps, 1, 64); ps += __shfl_xor(ps, 2, 64);
        pd += __shfl_xor(pd, 1, 64); pd += __shfl_xor(pd, 2, 64);
        if (seg == 0) { as2[rg] = ps; ad2[rg] = pd; }
    }
}

// one wave per node; 4 groups of 16 lanes x 4 edges per iteration = 16 gathers in flight.
__global__ void layer2_aggr(const __half* __restrict__ h2, const int* __restrict__ rowstart,
                            const int* __restrict__ srclist,
                            const float* __restrict__ as2, const float* __restrict__ ad2,
                            const float* __restrict__ b2, float* __restrict__ out2) {
    int wid = threadIdx.x >> 6, lane = threadIdx.x & 63;
    int nid = blockIdx.x * 4 + wid;
    int q = lane >> 4, c = lane & 15;
    int beg = __builtin_amdgcn_readfirstlane(rowstart[nid]);
    int end = __builtin_amdgcn_readfirstlane(rowstart[nid + 1]);
    float ad = ad2[nid];
    const __half* hb = h2 + c * 4;
    __half2 z16 = __float2half2_rn(0.f);
    __half2 acc0 = z16, acc1 = z16;
    float zs = 0.f;
    for (int i0 = beg; i0 < end; i0 += 16) {
#pragma unroll
        for (int u = 0; u < 4; ++u) {
            int i = i0 + q + 4 * u;
            bool valid = i < end;
            int s = valid ? srclist[i] : 0;
            float2 gv = *(const float2*)(hb + (size_t)s * 64);   // 8 B = 4 dims
            float e = as2[s] + ad;
            e = fmaxf(e, NEG_SLOPE * e);
            float w = valid ? __expf(e) : 0.f;
            zs += w;
            __half2 wh = __float2half2_rn(w);
            acc0 = __hfma2(wh, *(__half2*)&gv.x, acc0);
            acc1 = __hfma2(wh, *(__half2*)&gv.y, acc1);
        }
    }
    float2 f0 = __half22float2(acc0), f1 = __half22float2(acc1);
    float ax = f0.x, ay = f0.y, az = f1.x, aw = f1.y;
#pragma unroll
    for (int off = 16; off < 64; off <<= 1) {
        ax += __shfl_xor(ax, off, 64);
        ay += __shfl_xor(ay, off, 64);
        az += __shfl_xor(az, off, 64);
        aw += __shfl_xor(aw, off, 64);
        zs += __shfl_xor(zs, off, 64);
    }
    if (lane < 16) {
        float rz = 1.f / zs;
        float4 bo = ((const float4*)b2)[c];
        float4 st = make_float4(ax * rz + bo.x, ay * rz + bo.y,
                                az * rz + bo.z, aw * rz + bo.w);
        *(float4*)(out2 + (size_t)nid * 64 + c * 4) = st;
    }
}

// ---------------- final mean over nodes ----------------

__global__ void reduce_kernel(const float* __restrict__ out2, float* __restrict__ dout) {
    int t = threadIdx.x;
    int col = t & 63, sub = t >> 6;
    float acc = 0.f;
    for (int r = blockIdx.x * 4 + sub; r < NNODES; r += 256 * 4)
        acc += out2[r * 64 + col];
    __shared__ float sh[256];
    sh[t] = acc;
    __syncthreads();
    if (t < 64) {
        float v = sh[t] + sh[t + 64] + sh[t + 128] + sh[t + 192];
        atomicAdd(&dout[t], v * (1.0f / NNODES));
    }
}

// ---------------- launch ----------------

extern "C" void kernel_launch(void* const* d_in, const int* in_sizes, int n_in,
                              void* d_out, int out_size, void* d_ws, size_t ws_size,
                              hipStream_t stream) {
    const float* x        = (const float*)d_in[0];
    const int*   ei       = (const int*)d_in[1];   // [2, E] -> src row then dst row
    const float* W1       = (const float*)d_in[2];
    const float* att_src1 = (const float*)d_in[3];
    const float* att_dst1 = (const float*)d_in[4];
    const float* b1       = (const float*)d_in[5];
    const float* W2       = (const float*)d_in[6];
    const float* att_src2 = (const float*)d_in[7];
    const float* att_dst2 = (const float*)d_in[8];
    const float* b2       = (const float*)d_in[9];
    float* out = (float*)d_out;

    char* ws = (char*)d_ws;
    size_t off = 0;
    auto take = [&](size_t bytes) -> char* {
        char* p = ws + off;
        off = (off + bytes + 255) & ~(size_t)255;
        return p;
    };
    int*      bucket_cnt = (int*)take((size_t)NB_NODE * CNTSTRIDE * sizeof(int));
    int*      bucketbuf  = (int*)take((size_t)NB_NODE * CAPB * sizeof(int));
    int*      rowstart   = (int*)take((NNODES + 1) * sizeof(int));
    int*      partials   = (int*)take(256 * sizeof(int));
    int*      blockoff   = (int*)take(256 * sizeof(int));
    int*      srclist    = (int*)take(((size_t)NTOT + 16) * sizeof(int));
    float*    x16        = (float*)take((size_t)NNODES * 16 * sizeof(float));
    float*    asrc4      = (float*)take((size_t)NNODES * 4 * sizeof(float));
    float*    adst4      = (float*)take((size_t)NNODES * 4 * sizeof(float));
    __half*   out1       = (__half*)take((size_t)NNODES * 256 * sizeof(__half));
    _Float16* W2T        = (_Float16*)take(64 * 256 * sizeof(_Float16));
    __half*   h2         = (__half*)take((size_t)NNODES * 64 * sizeof(__half));
    float*    as2        = (float*)take((size_t)NNODES * sizeof(float));
    float*    ad2        = (float*)take((size_t)NNODES * sizeof(float));
    float*    out2       = (float*)take((size_t)NNODES * 64 * sizeof(float));

    const int* srcs = ei;
    const int* dsts = ei + NEDGES;

    hipMemsetAsync(d_out, 0, 64 * sizeof(float), stream);

    setup_kernel<<<NB_NODE, 256, 0, stream>>>(x, W1, att_src1, att_dst1, W2,
                                              bucket_cnt, x16, asrc4, adst4, W2T);
    bucket_scatter<<<NCHUNK, 256, 0, stream>>>(srcs, dsts, bucket_cnt, bucketbuf);
    scanA<<<NB_NODE, 256, 0, stream>>>(bucket_cnt, bucketbuf, rowstart, partials);
    scanB<<<1, 256, 0, stream>>>(partials, blockoff, rowstart, NB_NODE);
    scanC<<<NB_NODE, 256, 0, stream>>>(rowstart, blockoff);
    local_sort<<<NB_NODE, 256, 0, stream>>>(bucket_cnt, bucketbuf, rowstart, srclist);

    layer1_aggr<<<NNODES / 4, 256, 0, stream>>>(x16, rowstart, srclist, asrc4, adst4,
                                                W1, b1, out1);

    layer2_gemm<<<(NNODES + 63) / 64, 256, 0, stream>>>(out1, W2T, h2, att_src2, att_dst2,
                                                        as2, ad2);
    layer2_aggr<<<NNODES / 4, 256, 0, stream>>>(h2, rowstart, srclist, as2, ad2, b2, out2);

    reduce_kernel<<<256, 256, 0, stream>>>(out2, out);
}